// Round 4
// baseline (804.071 us; speedup 1.0000x reference)
//
#include <hip/hip_runtime.h>

typedef _Float16 f16;
typedef _Float16 f16x8 __attribute__((ext_vector_type(8)));
typedef float f32x4 __attribute__((ext_vector_type(4)));

#define NROWS 32768
#define BR 32
#define TS 28

#define MFMA16(A, B, C) __builtin_amdgcn_mfma_f32_16x16x32_f16((A), (B), (C), 0, 0, 0)
// Pin a weight fragment into the AGPR half of the unified register file.
// gfx950 MFMA reads A/B operands directly from AGPRs (ISA §10), while
// "+v" pins (R3) forced all 108 weight regs into the arch-VGPR partition
// and caused the 10 MB/launch scratch spill.
#define KEEPA(v) asm volatile("" : "+a"(v))

__device__ __forceinline__ f32x4 splat4(float v) { f32x4 r = {v, v, v, v}; return r; }
__device__ __forceinline__ float frcp(float v) { return __builtin_amdgcn_rcpf(v); }
__device__ __forceinline__ float fsig(float v) { return frcp(1.f + __expf(-v)); }
__device__ __forceinline__ float ftanh(float v) {
  float e = __expf(v + v);
  return 1.f - 2.f * frcp(e + 1.f);
}

// ---------------------------------------------------------------------------
// Prep: f32 weights -> f16 MFMA B-fragments in d_ws.
//   lane l, elem i -> col n = nt*16 + (l&15), k = kt*32 + (l>>4)*8 + i
// frag index space: wih1: 0..23 (K=28 zero-padded to 32)
//                   whh1: 24 + nt*4 + kt
//                   wih2: 120 + nt*4 + kt
//                   whh2: 216 + nt*4 + kt
// ---------------------------------------------------------------------------
__global__ void prep_weights(const float* __restrict__ wih1,
                             const float* __restrict__ whh1,
                             const float* __restrict__ wih2,
                             const float* __restrict__ whh2,
                             f16* __restrict__ wsf) {
  const int f = blockIdx.x;       // 0..311
  const int lane = threadIdx.x;   // 0..63
  const float* src;
  int K, nt, kt;
  if (f < 24)       { src = wih1; K = 28;  nt = f;             kt = 0; }
  else if (f < 120) { src = whh1; K = 128; int i = f - 24;  nt = i >> 2; kt = i & 3; }
  else if (f < 216) { src = wih2; K = 128; int i = f - 120; nt = i >> 2; kt = i & 3; }
  else              { src = whh2; K = 128; int i = f - 216; nt = i >> 2; kt = i & 3; }
  const int n  = nt * 16 + (lane & 15);
  const int k0 = kt * 32 + (lane >> 4) * 8;
  f16x8 pack;
#pragma unroll
  for (int i = 0; i < 8; i++) {
    const int k = k0 + i;
    float v = (k < K) ? src[n * K + k] : 0.f;
    pack[i] = (f16)v;
  }
  ((f16x8*)wsf)[f * 64 + lane] = pack;
}

// ---------------------------------------------------------------------------
// Main: persistent 28-step 2-layer GRU. 8 waves/block, BR=32 rows/block.
// Wave w owns h-dims [16w,16w+16): gate col tiles {w, 8+w, 16+w} (r,z,n).
// Register plan (256 combined regs/wave at 2 waves/SIMD):
//   AGPR: Wih1(12) + Wih2(48) + Whh2(48) [KEEPA-pinned] + acc(32) = 140
//   VGPR: ax dbuf(32) + h-state(16) + biases(8) + addr/temps       ~106
// Whh1 streams from LDS (96 KiB); h1/h2 via double-buffered XOR-swizzled
// f16 LDS tiles; x fragments for t+1 prefetched during layer-2 compute.
// ---------------------------------------------------------------------------
__global__ __launch_bounds__(512, 2) void gru_main(
    const float* __restrict__ x,
    const float* __restrict__ bih1, const float* __restrict__ bhh1,
    const float* __restrict__ bih2, const float* __restrict__ bhh2,
    const float* __restrict__ wout, const float* __restrict__ bout,
    const f16* __restrict__ wsf,
    float* __restrict__ out) {
  __shared__ __align__(16) f16 h1b[2][BR * 128];
  __shared__ __align__(16) f16 h2b[2][BR * 128];
  __shared__ __align__(16) f16 wsh[96 * 512];   // Whh1: 96 frags x 1 KiB

  const int tid  = threadIdx.x;
  const int wv   = tid >> 6;    // wave 0..7
  const int lane = tid & 63;
  const int lr   = lane & 15;   // A-row / B-col / D-col index
  const int kg   = lane >> 4;   // k-group (A/B) and D row-group
  const int row0 = blockIdx.x * BR;
  const int d    = wv * 16 + lr;  // this lane's h-dim (gate column)
  const int sw   = (lr & 7) << 3; // XOR swizzle (half units); rt*16 = 0 mod 8

  const f16x8* wf = (const f16x8*)wsf;

  // stage Whh1 -> LDS; zero-init h state buffers (h=0 at t=0)
  {
    f16x8* wd = (f16x8*)wsh;
    const f16x8* wsrc = wf + 24 * 64;
#pragma unroll
    for (int i = 0; i < 12; i++) wd[tid + 512 * i] = wsrc[tid + 512 * i];
    unsigned int* z1 = (unsigned int*)&h1b[0][0];
    unsigned int* z2 = (unsigned int*)&h2b[0][0];
#pragma unroll
    for (int i = 0; i < 8; i++) { z1[tid + 512 * i] = 0u; z2[tid + 512 * i] = 0u; }
  }

  // register-resident weights, pinned to AGPRs
  f16x8 Wih1[3], Wih2[3][4], Whh2[3][4];
#pragma unroll
  for (int g = 0; g < 3; g++) {
    const int nt = wv + g * 8;
    Wih1[g] = wf[nt * 64 + lane];
    KEEPA(Wih1[g]);
#pragma unroll
    for (int kt = 0; kt < 4; kt++) {
      Wih2[g][kt] = wf[(120 + nt * 4 + kt) * 64 + lane];
      KEEPA(Wih2[g][kt]);
      Whh2[g][kt] = wf[(216 + nt * 4 + kt) * 64 + lane];
      KEEPA(Whh2[g][kt]);
    }
  }

  // biases for this lane's gate column d
  const float b1r = bih1[d] + bhh1[d];
  const float b1z = bih1[128 + d] + bhh1[128 + d];
  const float b1i = bih1[256 + d];
  const float b1h = bhh1[256 + d];
  const float b2r = bih2[d] + bhh2[d];
  const float b2z = bih2[128 + d] + bhh2[128 + d];
  const float b2i = bih2[256 + d];
  const float b2h = bhh2[256 + d];

  // carried h state (f32)
  float h1s[2][4] = {{0, 0, 0, 0}, {0, 0, 0, 0}};
  float h2s[2][4] = {{0, 0, 0, 0}, {0, 0, 0, 0}};

  // x A-fragment loader (28 floats of row, f16-packed, zero-padded to K=32)
  auto load_ax = [&](int t, f16x8* axv) {
#pragma unroll
    for (int rt = 0; rt < 2; rt++) {
      const float* xp = x + (size_t)(row0 + rt * 16 + lr) * 784 + t * 28 + kg * 8;
      float4 p0 = *(const float4*)xp;
      float4 p1 = {0.f, 0.f, 0.f, 0.f};
      if (kg < 3) p1 = *(const float4*)(xp + 4);
      f16x8 a;
      a[0] = (f16)p0.x; a[1] = (f16)p0.y; a[2] = (f16)p0.z; a[3] = (f16)p0.w;
      a[4] = (f16)p1.x; a[5] = (f16)p1.y; a[6] = (f16)p1.z; a[7] = (f16)p1.w;
      axv[rt] = a;
    }
  };

  f16x8 axc[2], axn[2];
  load_ax(0, axc);

  __syncthreads();

  const f16x8* wlds = (const f16x8*)wsh;

  for (int t = 0; t < TS; t++) {
    const int cur = t & 1, nxt = cur ^ 1;
    f32x4 aR[2], aZ[2], aI[2], aH[2];
#pragma unroll
    for (int rt = 0; rt < 2; rt++) {
      aR[rt] = splat4(b1r); aZ[rt] = splat4(b1z);
      aI[rt] = splat4(b1i); aH[rt] = splat4(b1h);
    }
    // ---- layer-1 gates: kt-outer so only 3 Whh1 frags are live at a time
#pragma unroll
    for (int kt = 0; kt < 4; kt++) {
      f16x8 a0 = *(const f16x8*)&h1b[cur][(lr * 128 + kt * 32 + kg * 8) ^ sw];
      f16x8 a1 = *(const f16x8*)&h1b[cur][((16 + lr) * 128 + kt * 32 + kg * 8) ^ sw];
      f16x8 w0 = wlds[((wv     ) * 4 + kt) * 64 + lane];
      f16x8 w1 = wlds[((wv +  8) * 4 + kt) * 64 + lane];
      f16x8 w2 = wlds[((wv + 16) * 4 + kt) * 64 + lane];
      aR[0] = MFMA16(a0, w0, aR[0]); aR[1] = MFMA16(a1, w0, aR[1]);
      aZ[0] = MFMA16(a0, w1, aZ[0]); aZ[1] = MFMA16(a1, w1, aZ[1]);
      aH[0] = MFMA16(a0, w2, aH[0]); aH[1] = MFMA16(a1, w2, aH[1]);
    }
    aR[0] = MFMA16(axc[0], Wih1[0], aR[0]); aR[1] = MFMA16(axc[1], Wih1[0], aR[1]);
    aZ[0] = MFMA16(axc[0], Wih1[1], aZ[0]); aZ[1] = MFMA16(axc[1], Wih1[1], aZ[1]);
    aI[0] = MFMA16(axc[0], Wih1[2], aI[0]); aI[1] = MFMA16(axc[1], Wih1[2], aI[1]);

    // ---- layer-1 elementwise: D lane map col=lane&15(=d), row=kg*4+i
#pragma unroll
    for (int rt = 0; rt < 2; rt++) {
#pragma unroll
      for (int i = 0; i < 4; i++) {
        float rg = fsig(aR[rt][i]);
        float zg = fsig(aZ[rt][i]);
        float nn = ftanh(fmaf(rg, aH[rt][i], aI[rt][i]));
        float hp = h1s[rt][i];
        float hn = fmaxf(fmaf(zg, hp - nn, nn), 0.f);   // relu((1-z)n+zh)
        h1s[rt][i] = hn;
        const int rr = rt * 16 + kg * 4 + i;
        h1b[nxt][(rr * 128 + d) ^ ((rr & 7) << 3)] = (f16)hn;
      }
    }
    __syncthreads();

    // prefetch next step's x fragments; loads overlap layer-2 compute
    load_ax(t + 1 < TS ? t + 1 : t, axn);

    // ---- layer-2 gates: acc = bias + h1_new@Wih2^T + h2@Whh2^T
#pragma unroll
    for (int rt = 0; rt < 2; rt++) {
      aR[rt] = splat4(b2r); aZ[rt] = splat4(b2z);
      aI[rt] = splat4(b2i); aH[rt] = splat4(b2h);
    }
#pragma unroll
    for (int rt = 0; rt < 2; rt++) {
#pragma unroll
      for (int kt = 0; kt < 4; kt++) {
        f16x8 a1 = *(const f16x8*)&h1b[nxt][((rt * 16 + lr) * 128 + kt * 32 + kg * 8) ^ sw];
        f16x8 a2 = *(const f16x8*)&h2b[cur][((rt * 16 + lr) * 128 + kt * 32 + kg * 8) ^ sw];
        aR[rt] = MFMA16(a1, Wih2[0][kt], aR[rt]);
        aZ[rt] = MFMA16(a1, Wih2[1][kt], aZ[rt]);
        aI[rt] = MFMA16(a1, Wih2[2][kt], aI[rt]);
        aR[rt] = MFMA16(a2, Whh2[0][kt], aR[rt]);
        aZ[rt] = MFMA16(a2, Whh2[1][kt], aZ[rt]);
        aH[rt] = MFMA16(a2, Whh2[2][kt], aH[rt]);
      }
    }
#pragma unroll
    for (int rt = 0; rt < 2; rt++) {
#pragma unroll
      for (int i = 0; i < 4; i++) {
        float rg = fsig(aR[rt][i]);
        float zg = fsig(aZ[rt][i]);
        float nn = ftanh(fmaf(rg, aH[rt][i], aI[rt][i]));
        float hp = h2s[rt][i];
        float hn = fmaxf(fmaf(zg, hp - nn, nn), 0.f);
        h2s[rt][i] = hn;
        const int rr = rt * 16 + kg * 4 + i;
        h2b[nxt][(rr * 128 + d) ^ ((rr & 7) << 3)] = (f16)hn;
      }
    }
    __syncthreads();

    axc[0] = axn[0]; axc[1] = axn[1];
  }

  // ---- epilogue: out[row,col] = h2 . wout[col,:] + bout[col]
  // TS=28 even -> final h2 lives in h2b[0]
  const int orow = tid >> 4;   // 0..31
  const int ocol = tid & 15;   // 0..15, active < 10
  if (ocol < 10) {
    const f16* hb = h2b[0];
    float s = bout[ocol];
#pragma unroll 8
    for (int k = 0; k < 128; k++) {
      float hv = (float)hb[(orow * 128 + k) ^ ((orow & 7) << 3)];
      s = fmaf(hv, wout[ocol * 128 + k], s);
    }
    out[(size_t)(row0 + orow) * 10 + ocol] = s;
  }
}

extern "C" void kernel_launch(void* const* d_in, const int* in_sizes, int n_in,
                              void* d_out, int out_size, void* d_ws, size_t ws_size,
                              hipStream_t stream) {
  const float* x    = (const float*)d_in[0];
  const float* wih1 = (const float*)d_in[1];
  const float* whh1 = (const float*)d_in[2];
  const float* bih1 = (const float*)d_in[3];
  const float* bhh1 = (const float*)d_in[4];
  const float* wih2 = (const float*)d_in[5];
  const float* whh2 = (const float*)d_in[6];
  const float* bih2 = (const float*)d_in[7];
  const float* bhh2 = (const float*)d_in[8];
  const float* wout = (const float*)d_in[9];
  const float* bout = (const float*)d_in[10];
  f16* wsf   = (f16*)d_ws;
  float* out = (float*)d_out;

  prep_weights<<<312, 64, 0, stream>>>(wih1, whh1, wih2, whh2, wsf);
  gru_main<<<NROWS / BR, 512, 0, stream>>>(x, bih1, bhh1, bih2, bhh2,
                                           wout, bout, wsf, out);
}

// Round 5
// 613.877 us; speedup vs baseline: 1.3098x; 1.3098x over previous
//
#include <hip/hip_runtime.h>

typedef _Float16 f16;
typedef _Float16 f16x8 __attribute__((ext_vector_type(8)));
typedef float f32x4 __attribute__((ext_vector_type(4)));

#define NROWS 32768
#define BR 32
#define TS 28

#define MFMA16(A, B, C) __builtin_amdgcn_mfma_f32_16x16x32_f16((A), (B), (C), 0, 0, 0)

__device__ __forceinline__ f32x4 splat4(float v) { f32x4 r = {v, v, v, v}; return r; }
__device__ __forceinline__ float frcp(float v) { return __builtin_amdgcn_rcpf(v); }
__device__ __forceinline__ float fsig(float v) { return frcp(1.f + __expf(-v)); }
__device__ __forceinline__ float ftanh(float v) {
  float e = __expf(v + v);
  return 1.f - 2.f * frcp(e + 1.f);
}

// ---------------------------------------------------------------------------
// Prep: f32 weights -> f16 MFMA B-fragments in d_ws.
//   lane l, elem i -> col n = nt*16 + (l&15), k = kt*32 + (l>>4)*8 + i
// frag index space: wih1: 0..23 (K=28 zero-padded to 32)
//                   whh1: 24 + nt*4 + kt
//                   wih2: 120 + nt*4 + kt
//                   whh2: 216 + nt*4 + kt
// ---------------------------------------------------------------------------
__global__ void prep_weights(const float* __restrict__ wih1,
                             const float* __restrict__ whh1,
                             const float* __restrict__ wih2,
                             const float* __restrict__ whh2,
                             f16* __restrict__ wsf) {
  const int f = blockIdx.x;       // 0..311
  const int lane = threadIdx.x;   // 0..63
  const float* src;
  int K, nt, kt;
  if (f < 24)       { src = wih1; K = 28;  nt = f;             kt = 0; }
  else if (f < 120) { src = whh1; K = 128; int i = f - 24;  nt = i >> 2; kt = i & 3; }
  else if (f < 216) { src = wih2; K = 128; int i = f - 120; nt = i >> 2; kt = i & 3; }
  else              { src = whh2; K = 128; int i = f - 216; nt = i >> 2; kt = i & 3; }
  const int n  = nt * 16 + (lane & 15);
  const int k0 = kt * 32 + (lane >> 4) * 8;
  f16x8 pack;
#pragma unroll
  for (int i = 0; i < 8; i++) {
    const int k = k0 + i;
    float v = (k < K) ? src[n * K + k] : 0.f;
    pack[i] = (f16)v;
  }
  ((f16x8*)wsf)[f * 64 + lane] = pack;
}

// ---------------------------------------------------------------------------
// Main: layer-pipelined persistent GRU. 8 waves/block, BR=32 rows/block.
// Phase p (p=0..TS) computes L1[t=p] AND L2[t=p-1] together (independent:
// L1[p] needs {h1[p-1], x[p]}, L2[p-1] needs {h1[p-1], h2[p-2]}), sharing
// the h1[p-1] A-fragments between both GEMMs. ONE barrier per phase
// (29 total vs 56 in the 2-barrier/step version).
// Buffers: phase p reads h1b[p&1]/h2b[p&1], writes h1b[p&1^1]/h2b[p&1^1].
// Zero-init: h1b[0] (read @p=0) and h2b[1] (read @p=1).
// LDS: Whh1 (96K) + Wih1 (24K) streamed; h dbufs 32K -> 152 KiB total.
// Registers: Wih2+Whh2 (96) + acc (64) + temps; no pins (R4: "+a" pins
// catastrophically spill; R3: "+v" pins force arch-partition pressure).
// ---------------------------------------------------------------------------
__global__ __launch_bounds__(512, 2) void gru_main(
    const float* __restrict__ x,
    const float* __restrict__ bih1, const float* __restrict__ bhh1,
    const float* __restrict__ bih2, const float* __restrict__ bhh2,
    const float* __restrict__ wout, const float* __restrict__ bout,
    const f16* __restrict__ wsf,
    float* __restrict__ out) {
  __shared__ __align__(16) f16 h1b[2][BR * 128];
  __shared__ __align__(16) f16 h2b[2][BR * 128];
  __shared__ __align__(16) f16 wsh1[96 * 512];   // Whh1 frags
  __shared__ __align__(16) f16 wshx[24 * 512];   // Wih1 frags

  const int tid  = threadIdx.x;
  const int wv   = tid >> 6;    // wave 0..7
  const int lane = tid & 63;
  const int lr   = lane & 15;   // A-row / B-col / D-col index
  const int kg   = lane >> 4;   // k-group (A/B) and D row-group
  const int row0 = blockIdx.x * BR;
  const int d    = wv * 16 + lr;  // this lane's h-dim (gate column)
  const int sw   = (lr & 7) << 3; // XOR swizzle (f16-index units)

  const f16x8* wf = (const f16x8*)wsf;

  // stage Whh1 + Wih1 -> LDS; zero-init the phase-0/1 read buffers
  {
    f16x8* wd1 = (f16x8*)wsh1;
    const f16x8* ws1 = wf + 24 * 64;
#pragma unroll
    for (int i = 0; i < 12; i++) wd1[tid + 512 * i] = ws1[tid + 512 * i];
    f16x8* wdx = (f16x8*)wshx;
#pragma unroll
    for (int i = 0; i < 3; i++) wdx[tid + 512 * i] = wf[tid + 512 * i];
    unsigned int* z1 = (unsigned int*)&h1b[0][0];
    unsigned int* z2 = (unsigned int*)&h2b[1][0];
#pragma unroll
    for (int i = 0; i < 4; i++) { z1[tid + 512 * i] = 0u; z2[tid + 512 * i] = 0u; }
  }

  // register-resident layer-2 weights (96 VGPRs)
  f16x8 Wih2[3][4], Whh2[3][4];
#pragma unroll
  for (int g = 0; g < 3; g++) {
    const int nt = wv + g * 8;
#pragma unroll
    for (int kt = 0; kt < 4; kt++) {
      Wih2[g][kt] = wf[(120 + nt * 4 + kt) * 64 + lane];
      Whh2[g][kt] = wf[(216 + nt * 4 + kt) * 64 + lane];
    }
  }

  // biases for this lane's gate column d
  const float b1r = bih1[d] + bhh1[d];
  const float b1z = bih1[128 + d] + bhh1[128 + d];
  const float b1i = bih1[256 + d];
  const float b1h = bhh1[256 + d];
  const float b2r = bih2[d] + bhh2[d];
  const float b2z = bih2[128 + d] + bhh2[128 + d];
  const float b2i = bih2[256 + d];
  const float b2h = bhh2[256 + d];

  // carried h state (f32 copies for the (1-z)n+zh blend)
  float h1s[2][4] = {{0, 0, 0, 0}, {0, 0, 0, 0}};
  float h2s[2][4] = {{0, 0, 0, 0}, {0, 0, 0, 0}};

  const float* xp0 = x + (size_t)(row0 + lr) * 784 + kg * 8;        // rt=0 rows
  const float* xp1 = xp0 + (size_t)16 * 784;                        // rt=1 rows

  const f16x8* wl1 = (const f16x8*)wsh1;
  const f16x8* wlx = (const f16x8*)wshx;

  __syncthreads();

  auto phase = [&](int p, bool L1, bool L2) {
    const int cur = p & 1;
    const f16* h1r = h1b[cur];
    const f16* h2r = h2b[cur];
    f16* h1w = h1b[cur ^ 1];
    f16* h2w = h2b[cur ^ 1];

    // 1) issue x raw loads early; consumed after the kt-loop
    float4 q00, q01, q10, q11;
    if (L1) {
      const float* a = xp0 + p * 28;
      const float* b = xp1 + p * 28;
      q00 = *(const float4*)a;
      q10 = *(const float4*)b;
      float4 zz = {0.f, 0.f, 0.f, 0.f};
      q01 = zz; q11 = zz;
      if (kg < 3) { q01 = *(const float4*)(a + 4); q11 = *(const float4*)(b + 4); }
    }

    // 2) init accumulators with biases
    f32x4 aR1[2], aZ1[2], aI1[2], aH1[2];
    f32x4 aR2[2], aZ2[2], aI2[2], aH2[2];
    if (L1) {
#pragma unroll
      for (int rt = 0; rt < 2; rt++) {
        aR1[rt] = splat4(b1r); aZ1[rt] = splat4(b1z);
        aI1[rt] = splat4(b1i); aH1[rt] = splat4(b1h);
      }
    }
    if (L2) {
#pragma unroll
      for (int rt = 0; rt < 2; rt++) {
        aR2[rt] = splat4(b2r); aZ2[rt] = splat4(b2z);
        aI2[rt] = splat4(b2i); aH2[rt] = splat4(b2h);
      }
    }

    // 3) fused K-loop: h1[p-1] A-frags feed BOTH Whh1 (L1) and Wih2 (L2)
#pragma unroll
    for (int kt = 0; kt < 4; kt++) {
      const int o0 = (lr * 128 + kt * 32 + kg * 8) ^ sw;
      const int o1 = ((16 + lr) * 128 + kt * 32 + kg * 8) ^ sw;
      f16x8 a10 = *(const f16x8*)&h1r[o0];
      f16x8 a11 = *(const f16x8*)&h1r[o1];
      if (L1) {
        f16x8 w0 = wl1[((wv     ) * 4 + kt) * 64 + lane];
        f16x8 w1 = wl1[((wv +  8) * 4 + kt) * 64 + lane];
        f16x8 w2 = wl1[((wv + 16) * 4 + kt) * 64 + lane];
        aR1[0] = MFMA16(a10, w0, aR1[0]); aR1[1] = MFMA16(a11, w0, aR1[1]);
        aZ1[0] = MFMA16(a10, w1, aZ1[0]); aZ1[1] = MFMA16(a11, w1, aZ1[1]);
        aH1[0] = MFMA16(a10, w2, aH1[0]); aH1[1] = MFMA16(a11, w2, aH1[1]);
      }
      if (L2) {
        f16x8 a20 = *(const f16x8*)&h2r[o0];
        f16x8 a21 = *(const f16x8*)&h2r[o1];
        aR2[0] = MFMA16(a10, Wih2[0][kt], aR2[0]); aR2[1] = MFMA16(a11, Wih2[0][kt], aR2[1]);
        aZ2[0] = MFMA16(a10, Wih2[1][kt], aZ2[0]); aZ2[1] = MFMA16(a11, Wih2[1][kt], aZ2[1]);
        aI2[0] = MFMA16(a10, Wih2[2][kt], aI2[0]); aI2[1] = MFMA16(a11, Wih2[2][kt], aI2[1]);
        aR2[0] = MFMA16(a20, Whh2[0][kt], aR2[0]); aR2[1] = MFMA16(a21, Whh2[0][kt], aR2[1]);
        aZ2[0] = MFMA16(a20, Whh2[1][kt], aZ2[0]); aZ2[1] = MFMA16(a21, Whh2[1][kt], aZ2[1]);
        aH2[0] = MFMA16(a20, Whh2[2][kt], aH2[0]); aH2[1] = MFMA16(a21, Whh2[2][kt], aH2[1]);
      }
    }

    // 4) x contribution (loads from step 1 have had the kt-loop to land)
    if (L1) {
      f16x8 ax0, ax1;
      ax0[0] = (f16)q00.x; ax0[1] = (f16)q00.y; ax0[2] = (f16)q00.z; ax0[3] = (f16)q00.w;
      ax0[4] = (f16)q01.x; ax0[5] = (f16)q01.y; ax0[6] = (f16)q01.z; ax0[7] = (f16)q01.w;
      ax1[0] = (f16)q10.x; ax1[1] = (f16)q10.y; ax1[2] = (f16)q10.z; ax1[3] = (f16)q10.w;
      ax1[4] = (f16)q11.x; ax1[5] = (f16)q11.y; ax1[6] = (f16)q11.z; ax1[7] = (f16)q11.w;
      f16x8 u0 = wlx[(wv     ) * 64 + lane];
      f16x8 u1 = wlx[(wv +  8) * 64 + lane];
      f16x8 u2 = wlx[(wv + 16) * 64 + lane];
      aR1[0] = MFMA16(ax0, u0, aR1[0]); aR1[1] = MFMA16(ax1, u0, aR1[1]);
      aZ1[0] = MFMA16(ax0, u1, aZ1[0]); aZ1[1] = MFMA16(ax1, u1, aZ1[1]);
      aI1[0] = MFMA16(ax0, u2, aI1[0]); aI1[1] = MFMA16(ax1, u2, aI1[1]);
    }

    // 5) elementwise. L2 first (its deps completed in the kt-loop).
    //    D lane map: col = lane&15 (=d), row = kg*4+i (+16*rt)
    if (L2) {
#pragma unroll
      for (int rt = 0; rt < 2; rt++) {
#pragma unroll
        for (int i = 0; i < 4; i++) {
          float rg = fsig(aR2[rt][i]);
          float zg = fsig(aZ2[rt][i]);
          float nn = ftanh(fmaf(rg, aH2[rt][i], aI2[rt][i]));
          float hp = h2s[rt][i];
          float hn = fmaxf(fmaf(zg, hp - nn, nn), 0.f);   // relu((1-z)n+zh)
          h2s[rt][i] = hn;
          const int rr = rt * 16 + kg * 4 + i;
          h2w[(rr * 128 + d) ^ ((rr & 7) << 3)] = (f16)hn;
        }
      }
    }
    if (L1) {
#pragma unroll
      for (int rt = 0; rt < 2; rt++) {
#pragma unroll
        for (int i = 0; i < 4; i++) {
          float rg = fsig(aR1[rt][i]);
          float zg = fsig(aZ1[rt][i]);
          float nn = ftanh(fmaf(rg, aH1[rt][i], aI1[rt][i]));
          float hp = h1s[rt][i];
          float hn = fmaxf(fmaf(zg, hp - nn, nn), 0.f);
          h1s[rt][i] = hn;
          const int rr = rt * 16 + kg * 4 + i;
          h1w[(rr * 128 + d) ^ ((rr & 7) << 3)] = (f16)hn;
        }
      }
    }
    __syncthreads();
  };

  phase(0, true, false);
  for (int p = 1; p < TS; p++) phase(p, true, true);
  phase(TS, false, true);

  // ---- epilogue: out[row,col] = h2 . wout[col,:] + bout[col]
  // phase TS wrote h2[27] into h2b[(TS&1)^1] = h2b[1]
  const int orow = tid >> 4;   // 0..31
  const int ocol = tid & 15;   // 0..15, active < 10
  if (ocol < 10) {
    const f16* hb = h2b[1];
    float s = bout[ocol];
#pragma unroll 8
    for (int k = 0; k < 128; k++) {
      float hv = (float)hb[(orow * 128 + k) ^ ((orow & 7) << 3)];
      s = fmaf(hv, wout[ocol * 128 + k], s);
    }
    out[(size_t)(row0 + orow) * 10 + ocol] = s;
  }
}

extern "C" void kernel_launch(void* const* d_in, const int* in_sizes, int n_in,
                              void* d_out, int out_size, void* d_ws, size_t ws_size,
                              hipStream_t stream) {
  const float* x    = (const float*)d_in[0];
  const float* wih1 = (const float*)d_in[1];
  const float* whh1 = (const float*)d_in[2];
  const float* bih1 = (const float*)d_in[3];
  const float* bhh1 = (const float*)d_in[4];
  const float* wih2 = (const float*)d_in[5];
  const float* whh2 = (const float*)d_in[6];
  const float* bih2 = (const float*)d_in[7];
  const float* bhh2 = (const float*)d_in[8];
  const float* wout = (const float*)d_in[9];
  const float* bout = (const float*)d_in[10];
  f16* wsf   = (f16*)d_ws;
  float* out = (float*)d_out;

  prep_weights<<<312, 64, 0, stream>>>(wih1, whh1, wih2, whh2, wsf);
  gru_main<<<NROWS / BR, 512, 0, stream>>>(x, bih1, bhh1, bih2, bhh2,
                                           wout, bout, wsf, out);
}

// Round 6
// 592.995 us; speedup vs baseline: 1.3559x; 1.0352x over previous
//
#include <hip/hip_runtime.h>

typedef _Float16 f16;
typedef _Float16 f16x8 __attribute__((ext_vector_type(8)));
typedef float f32x4 __attribute__((ext_vector_type(4)));

#define NROWS 32768
#define BR 32
#define TS 28

#define MFMA16(A, B, C) __builtin_amdgcn_mfma_f32_16x16x32_f16((A), (B), (C), 0, 0, 0)

__device__ __forceinline__ f32x4 splat4(float v) { f32x4 r = {v, v, v, v}; return r; }
__device__ __forceinline__ float frcp(float v) { return __builtin_amdgcn_rcpf(v); }
__device__ __forceinline__ float fsig(float v) { return frcp(1.f + __expf(-v)); }
__device__ __forceinline__ float ftanh(float v) {
  float e = __expf(v + v);
  return 1.f - 2.f * frcp(e + 1.f);
}

// ---------------------------------------------------------------------------
// Prep: f32 weights -> f16 MFMA B-fragments in d_ws.
//   lane l, elem i -> col n = nt*16 + (l&15), k = kt*32 + (l>>4)*8 + i
// frag index space: wih1: 0..23 (K=28 zero-padded to 32)
//                   whh1: 24 + nt*4 + kt
//                   wih2: 120 + nt*4 + kt
//                   whh2: 216 + nt*4 + kt
// ---------------------------------------------------------------------------
__global__ void prep_weights(const float* __restrict__ wih1,
                             const float* __restrict__ whh1,
                             const float* __restrict__ wih2,
                             const float* __restrict__ whh2,
                             f16* __restrict__ wsf) {
  const int f = blockIdx.x;       // 0..311
  const int lane = threadIdx.x;   // 0..63
  const float* src;
  int K, nt, kt;
  if (f < 24)       { src = wih1; K = 28;  nt = f;             kt = 0; }
  else if (f < 120) { src = whh1; K = 128; int i = f - 24;  nt = i >> 2; kt = i & 3; }
  else if (f < 216) { src = wih2; K = 128; int i = f - 120; nt = i >> 2; kt = i & 3; }
  else              { src = whh2; K = 128; int i = f - 216; nt = i >> 2; kt = i & 3; }
  const int n  = nt * 16 + (lane & 15);
  const int k0 = kt * 32 + (lane >> 4) * 8;
  f16x8 pack;
#pragma unroll
  for (int i = 0; i < 8; i++) {
    const int k = k0 + i;
    float v = (k < K) ? src[n * K + k] : 0.f;
    pack[i] = (f16)v;
  }
  ((f16x8*)wsf)[f * 64 + lane] = pack;
}

// ---------------------------------------------------------------------------
// Main: wave-specialized layer-pipelined GRU. 1024 threads = 16 waves.
// Waves 0-7  (grp=0): L1[p] = GRU(x[p], h1[p-1])       for p = 0..27
// Waves 8-15 (grp=1): L2[p-1] = GRU(h1[p-1], h2[p-2])  for p = 1..28
// Both run CONCURRENTLY in phase p; one barrier/phase (29 total).
// Design point: 128 VGPR/wave (4 waves/SIMD), zero spill:
//   regs: own-layer Whh (48) + acc 16 (rt sequential) + transients ~50
//   LDS:  Wih1 24K + Wih2 96K + h1/h2 dbufs 32K = 152K -> 1 block/CU
//   occupancy: 16 waves/CU (~47%) -- 2x the R5 structure's 8.
// R3/R4 lessons: no "+v"/"+a" register pins (both force spill paths).
// Buffers: phase p reads h*b[p&1], writes h*b[p&1^1].
// Zero-init: h1b[0] (read @p=0 by L1), h2b[1] (read @p=1 by L2).
// ---------------------------------------------------------------------------
__global__ __launch_bounds__(1024, 4) void gru_main(
    const float* __restrict__ x,
    const float* __restrict__ bih1, const float* __restrict__ bhh1,
    const float* __restrict__ bih2, const float* __restrict__ bhh2,
    const float* __restrict__ wout, const float* __restrict__ bout,
    const f16* __restrict__ wsf,
    float* __restrict__ out) {
  __shared__ __align__(16) f16 h1b[2][BR * 128];
  __shared__ __align__(16) f16 h2b[2][BR * 128];
  __shared__ __align__(16) f16 wshx[24 * 512];   // Wih1 frags (L1 waves)
  __shared__ __align__(16) f16 wsh2[96 * 512];   // Wih2 frags (L2 waves)

  const int tid  = threadIdx.x;
  const int wid  = tid >> 6;      // 0..15
  const int grp  = wid >> 3;      // 0 = L1, 1 = L2
  const int wv   = wid & 7;       // wave-within-group: h-dim tile
  const int lane = tid & 63;
  const int lr   = lane & 15;
  const int kg   = lane >> 4;
  const int row0 = blockIdx.x * BR;
  const int d    = wv * 16 + lr;  // this lane's gate column (h-dim)
  const int sw   = (lr & 7) << 3; // XOR swizzle (f16-index units)

  const f16x8* wf = (const f16x8*)wsf;

  // stage Wih1 + Wih2 -> LDS; zero-init phase-0/1 read buffers
  {
    f16x8* wdx = (f16x8*)wshx;                       // 1536 f16x8
    if (tid < 512) wdx[1024 + tid] = wf[1024 + tid];
    wdx[tid] = wf[tid];
    f16x8* wd2 = (f16x8*)wsh2;                       // 6144 f16x8
    const f16x8* ws2 = wf + 120 * 64;
#pragma unroll
    for (int i = 0; i < 6; i++) wd2[tid + 1024 * i] = ws2[tid + 1024 * i];
    unsigned int* z1 = (unsigned int*)&h1b[0][0];
    unsigned int* z2 = (unsigned int*)&h2b[1][0];
    z1[tid] = 0u; z1[tid + 1024] = 0u;
    z2[tid] = 0u; z2[tid + 1024] = 0u;
  }

  // own-layer recurrent weights in registers: Whh1 (grp 0) / Whh2 (grp 1)
  const int wbase = grp ? 216 : 24;
  f16x8 Wreg[3][4];
#pragma unroll
  for (int g = 0; g < 3; g++)
#pragma unroll
    for (int kt = 0; kt < 4; kt++)
      Wreg[g][kt] = wf[(wbase + (wv + g * 8) * 4 + kt) * 64 + lane];

  // own-layer biases only
  const float* bi = grp ? bih2 : bih1;
  const float* bh = grp ? bhh2 : bhh1;
  const float br_ = bi[d] + bh[d];
  const float bz_ = bi[128 + d] + bh[128 + d];
  const float bin = bi[256 + d];
  const float bhn = bh[256 + d];

  // carried f32 state for this wave's layer (its 2 row-tiles)
  float hs[2][4] = {{0, 0, 0, 0}, {0, 0, 0, 0}};

  const f16x8* wlx = (const f16x8*)wshx;
  const f16x8* wl2 = (const f16x8*)wsh2;

  __syncthreads();

  for (int p = 0; p <= TS; p++) {
    const int cur = p & 1;
    const f16* h1r = h1b[cur];
    f16* h1w = h1b[cur ^ 1];
    const f16* h2r = h2b[cur];
    f16* h2w = h2b[cur ^ 1];

    if (grp == 0) {
      if (p < TS) {
        // issue both row-tiles' x loads up front (hide global latency)
        float4 q[2][2];
#pragma unroll
        for (int rt = 0; rt < 2; rt++) {
          const float* a = x + (size_t)(row0 + rt * 16 + lr) * 784 + p * 28 + kg * 8;
          q[rt][0] = *(const float4*)a;
          float4 zz = {0.f, 0.f, 0.f, 0.f};
          q[rt][1] = zz;
          if (kg < 3) q[rt][1] = *(const float4*)(a + 4);
        }
#pragma unroll
        for (int rt = 0; rt < 2; rt++) {
          f32x4 aR = splat4(br_), aZ = splat4(bz_), aI = splat4(bin), aH = splat4(bhn);
          const int ro = (rt * 16 + lr) * 128;
#pragma unroll
          for (int kt = 0; kt < 4; kt++) {
            f16x8 a1 = *(const f16x8*)&h1r[(ro + kt * 32 + kg * 8) ^ sw];
            aR = MFMA16(a1, Wreg[0][kt], aR);
            aZ = MFMA16(a1, Wreg[1][kt], aZ);
            aH = MFMA16(a1, Wreg[2][kt], aH);
          }
          f16x8 ax;
          ax[0] = (f16)q[rt][0].x; ax[1] = (f16)q[rt][0].y;
          ax[2] = (f16)q[rt][0].z; ax[3] = (f16)q[rt][0].w;
          ax[4] = (f16)q[rt][1].x; ax[5] = (f16)q[rt][1].y;
          ax[6] = (f16)q[rt][1].z; ax[7] = (f16)q[rt][1].w;
          f16x8 u0 = wlx[(wv     ) * 64 + lane];
          f16x8 u1 = wlx[(wv +  8) * 64 + lane];
          f16x8 u2 = wlx[(wv + 16) * 64 + lane];
          aR = MFMA16(ax, u0, aR);
          aZ = MFMA16(ax, u1, aZ);
          aI = MFMA16(ax, u2, aI);
#pragma unroll
          for (int i = 0; i < 4; i++) {
            float rg = fsig(aR[i]);
            float zg = fsig(aZ[i]);
            float nn = ftanh(fmaf(rg, aH[i], aI[i]));
            float hp = hs[rt][i];
            float hn = fmaxf(fmaf(zg, hp - nn, nn), 0.f);  // relu((1-z)n+zh)
            hs[rt][i] = hn;
            const int rr = rt * 16 + kg * 4 + i;
            h1w[(rr * 128 + d) ^ ((rr & 7) << 3)] = (f16)hn;
          }
        }
      }
    } else {
      if (p >= 1) {
#pragma unroll
        for (int rt = 0; rt < 2; rt++) {
          f32x4 aR = splat4(br_), aZ = splat4(bz_), aI = splat4(bin), aH = splat4(bhn);
          const int ro = (rt * 16 + lr) * 128;
#pragma unroll
          for (int kt = 0; kt < 4; kt++) {
            const int o = (ro + kt * 32 + kg * 8) ^ sw;
            f16x8 a1 = *(const f16x8*)&h1r[o];
            f16x8 a2 = *(const f16x8*)&h2r[o];
            f16x8 u0 = wl2[((wv     ) * 4 + kt) * 64 + lane];
            f16x8 u1 = wl2[((wv +  8) * 4 + kt) * 64 + lane];
            f16x8 u2 = wl2[((wv + 16) * 4 + kt) * 64 + lane];
            aR = MFMA16(a1, u0, aR);
            aZ = MFMA16(a1, u1, aZ);
            aI = MFMA16(a1, u2, aI);
            aR = MFMA16(a2, Wreg[0][kt], aR);
            aZ = MFMA16(a2, Wreg[1][kt], aZ);
            aH = MFMA16(a2, Wreg[2][kt], aH);
          }
#pragma unroll
          for (int i = 0; i < 4; i++) {
            float rg = fsig(aR[i]);
            float zg = fsig(aZ[i]);
            float nn = ftanh(fmaf(rg, aH[i], aI[i]));
            float hp = hs[rt][i];
            float hn = fmaxf(fmaf(zg, hp - nn, nn), 0.f);
            hs[rt][i] = hn;
            const int rr = rt * 16 + kg * 4 + i;
            h2w[(rr * 128 + d) ^ ((rr & 7) << 3)] = (f16)hn;
          }
        }
      }
    }
    __syncthreads();
  }

  // ---- epilogue: out[row,col] = h2 . wout[col,:] + bout[col]
  // phase TS=28 wrote h2[27] into h2b[(28&1)^1] = h2b[1]
  const int orow = tid >> 4;   // 0..63; valid rows < 32
  const int ocol = tid & 15;   // active < 10
  if (orow < BR && ocol < 10) {
    const f16* hb = h2b[1];
    float s = bout[ocol];
#pragma unroll 8
    for (int k = 0; k < 128; k++) {
      float hv = (float)hb[(orow * 128 + k) ^ ((orow & 7) << 3)];
      s = fmaf(hv, wout[ocol * 128 + k], s);
    }
    out[(size_t)(row0 + orow) * 10 + ocol] = s;
  }
}

extern "C" void kernel_launch(void* const* d_in, const int* in_sizes, int n_in,
                              void* d_out, int out_size, void* d_ws, size_t ws_size,
                              hipStream_t stream) {
  const float* x    = (const float*)d_in[0];
  const float* wih1 = (const float*)d_in[1];
  const float* whh1 = (const float*)d_in[2];
  const float* bih1 = (const float*)d_in[3];
  const float* bhh1 = (const float*)d_in[4];
  const float* wih2 = (const float*)d_in[5];
  const float* whh2 = (const float*)d_in[6];
  const float* bih2 = (const float*)d_in[7];
  const float* bhh2 = (const float*)d_in[8];
  const float* wout = (const float*)d_in[9];
  const float* bout = (const float*)d_in[10];
  f16* wsf   = (f16*)d_ws;
  float* out = (float*)d_out;

  prep_weights<<<312, 64, 0, stream>>>(wih1, whh1, wih2, whh2, wsf);
  gru_main<<<NROWS / BR, 1024, 0, stream>>>(x, bih1, bhh1, bih2, bhh2,
                                            wout, bout, wsf, out);
}

// Round 7
// 503.776 us; speedup vs baseline: 1.5961x; 1.1771x over previous
//
#include <hip/hip_runtime.h>

typedef _Float16 f16;
typedef _Float16 f16x8 __attribute__((ext_vector_type(8)));
typedef float f32x4 __attribute__((ext_vector_type(4)));

#define NROWS 32768
#define BR 32
#define TS 28

#define MFMA16(A, B, C) __builtin_amdgcn_mfma_f32_16x16x32_f16((A), (B), (C), 0, 0, 0)

__device__ __forceinline__ f32x4 splat4(float v) { f32x4 r = {v, v, v, v}; return r; }
__device__ __forceinline__ float frcp(float v) { return __builtin_amdgcn_rcpf(v); }
__device__ __forceinline__ float fsig(float v) { return frcp(1.f + __expf(-v)); }
__device__ __forceinline__ float ftanh(float v) {
  float e = __expf(v + v);
  return 1.f - 2.f * frcp(e + 1.f);
}

// async 16B global -> LDS (dest = wave-uniform base + lane*16)
__device__ __forceinline__ void gload_lds16(const float* g, void* l) {
  __builtin_amdgcn_global_load_lds(
      (const __attribute__((address_space(1))) void*)g,
      (__attribute__((address_space(3))) void*)l, 16, 0, 0);
}

// ---------------------------------------------------------------------------
// Prep: f32 weights -> f16 MFMA B-fragments in d_ws.
//   lane l, elem i -> col n = nt*16 + (l&15), k = kt*32 + (l>>4)*8 + i
// frag index space: wih1: 0..23 (K=28 zero-padded to 32)
//                   whh1: 24 + nt*4 + kt
//                   wih2: 120 + nt*4 + kt
//                   whh2: 216 + nt*4 + kt
// ---------------------------------------------------------------------------
__global__ void prep_weights(const float* __restrict__ wih1,
                             const float* __restrict__ whh1,
                             const float* __restrict__ wih2,
                             const float* __restrict__ whh2,
                             f16* __restrict__ wsf) {
  const int f = blockIdx.x;       // 0..311
  const int lane = threadIdx.x;   // 0..63
  const float* src;
  int K, nt, kt;
  if (f < 24)       { src = wih1; K = 28;  nt = f;             kt = 0; }
  else if (f < 120) { src = whh1; K = 128; int i = f - 24;  nt = i >> 2; kt = i & 3; }
  else if (f < 216) { src = wih2; K = 128; int i = f - 120; nt = i >> 2; kt = i & 3; }
  else              { src = whh2; K = 128; int i = f - 216; nt = i >> 2; kt = i & 3; }
  const int n  = nt * 16 + (lane & 15);
  const int k0 = kt * 32 + (lane >> 4) * 8;
  f16x8 pack;
#pragma unroll
  for (int i = 0; i < 8; i++) {
    const int k = k0 + i;
    float v = (k < K) ? src[n * K + k] : 0.f;
    pack[i] = (f16)v;
  }
  ((f16x8*)wsf)[f * 64 + lane] = pack;
}

// ---------------------------------------------------------------------------
// Main: wave-specialized layer-pipelined GRU. 1024 threads = 16 waves.
// Waves 0-7  (grp=0): L1[p] = GRU(x[p], h1[p-1])       for p = 0..27
// Waves 8-15 (grp=1): L2[p-1] = GRU(h1[p-1], h2[p-2])  for p = 1..28
// One barrier/phase (29 total).
// R6 lesson: arch-VGPR budget at 4 waves/SIMD is 64 (other 64 are AGPR =
// Wreg 48 + acc 16); the f32 x-preload (16 regs) overflowed it -> 93 MB
// spill. Fix: x staged through LDS via global_load_lds, double-buffered;
// waves 0-3 issue phase p+1's 3.5 KB during phase p; the phase barrier's
// vmcnt(0) drain guarantees arrival. Arch demand now ~50 -> no spill.
// x LDS layout: 32-float rows, chunk c holds global chunk c^(row&7)
// (source-side swizzle, linear gload_lds dest) -> ds_read_b128 of the
// A-frags is bank-conflict-free. Chunk-7 garbage only reaches the kg=3
// high half, whose Wih1 B-rows (k=28..31) are zero-padded: harmless.
// LDS: h dbufs 32K + Wih1 24K + Wih2 96K + x dbuf 8K = 160K exactly.
// ---------------------------------------------------------------------------
__global__ __launch_bounds__(1024, 4) void gru_main(
    const float* __restrict__ x,
    const float* __restrict__ bih1, const float* __restrict__ bhh1,
    const float* __restrict__ bih2, const float* __restrict__ bhh2,
    const float* __restrict__ wout, const float* __restrict__ bout,
    const f16* __restrict__ wsf,
    float* __restrict__ out) {
  __shared__ __align__(16) f16 h1b[2][BR * 128];
  __shared__ __align__(16) f16 h2b[2][BR * 128];
  __shared__ __align__(16) f16 wshx[24 * 512];     // Wih1 frags (L1 waves)
  __shared__ __align__(16) f16 wsh2[96 * 512];     // Wih2 frags (L2 waves)
  __shared__ __align__(16) float xbuf[2][BR * 32]; // x staging, 2 x 4096 B

  const int tid  = threadIdx.x;
  const int wid  = tid >> 6;      // 0..15
  const int grp  = wid >> 3;      // 0 = L1, 1 = L2
  const int wv   = wid & 7;       // wave-within-group: h-dim tile
  const int lane = tid & 63;
  const int lr   = lane & 15;
  const int kg   = lane >> 4;
  const int row0 = blockIdx.x * BR;
  const int d    = wv * 16 + lr;  // this lane's gate column (h-dim)
  const int sw   = (lr & 7) << 3; // XOR swizzle (f16-index units)

  const f16x8* wf = (const f16x8*)wsf;

  // stage Wih1 + Wih2 -> LDS; zero-init phase-0/1 read buffers
  {
    f16x8* wdx = (f16x8*)wshx;                       // 1536 f16x8
    if (tid < 512) wdx[1024 + tid] = wf[1024 + tid];
    wdx[tid] = wf[tid];
    f16x8* wd2 = (f16x8*)wsh2;                       // 6144 f16x8
    const f16x8* ws2 = wf + 120 * 64;
#pragma unroll
    for (int i = 0; i < 6; i++) wd2[tid + 1024 * i] = ws2[tid + 1024 * i];
    unsigned int* z1 = (unsigned int*)&h1b[0][0];
    unsigned int* z2 = (unsigned int*)&h2b[1][0];
    z1[tid] = 0u; z1[tid + 1024] = 0u;
    z2[tid] = 0u; z2[tid + 1024] = 0u;
  }

  // own-layer recurrent weights in registers: Whh1 (grp 0) / Whh2 (grp 1)
  const int wbase = grp ? 216 : 24;
  f16x8 Wreg[3][4];
#pragma unroll
  for (int g = 0; g < 3; g++)
#pragma unroll
    for (int kt = 0; kt < 4; kt++)
      Wreg[g][kt] = wf[(wbase + (wv + g * 8) * 4 + kt) * 64 + lane];

  // own-layer biases
  const float* bi = grp ? bih2 : bih1;
  const float* bh = grp ? bhh2 : bhh1;
  const float br_ = bi[d] + bh[d];
  const float bz_ = bi[128 + d] + bh[128 + d];
  const float bin = bi[256 + d];
  const float bhn = bh[256 + d];

  // carried f32 state for this wave's layer (its 2 row-tiles)
  float hs[2][4] = {{0, 0, 0, 0}, {0, 0, 0, 0}};

  const f16x8* wlx = (const f16x8*)wshx;
  const f16x8* wl2 = (const f16x8*)wsh2;

  // x stage issuer: waves 0-3, 256 lanes cover 32 rows x 8 chunks of 16B.
  // LDS chunk (row,c) <- global chunk (row, c^(row&7)); chunk 7 clamped
  // to 6 (garbage, only read in the zero-weight kg=3 high half).
  auto issue_x = [&](int p, int nb) {
    if (wid < 4) {
      const int j  = wid * 64 + lane;   // 0..255
      const int xr = j >> 3;
      int cs = (j & 7) ^ (xr & 7);
      cs -= (cs == 7);
      const float* src = x + (size_t)(row0 + xr) * 784 + p * 28 + cs * 4;
      gload_lds16(src, (char*)&xbuf[nb][0] + wid * 1024);
    }
  };

  issue_x(0, 0);
  __syncthreads();

  for (int p = 0; p <= TS; p++) {
    const int cur = p & 1;
    const f16* h1r = h1b[cur];
    f16* h1w = h1b[cur ^ 1];
    const f16* h2r = h2b[cur];
    f16* h2w = h2b[cur ^ 1];

    // prefetch next phase's x tile (lands by the phase-end barrier)
    if (p + 1 < TS) issue_x(p + 1, cur ^ 1);

    if (grp == 0) {
      if (p < TS) {
#pragma unroll
        for (int rt = 0; rt < 2; rt++) {
          f32x4 aR = splat4(br_), aZ = splat4(bz_), aI = splat4(bin), aH = splat4(bhn);
          const int ro = (rt * 16 + lr) * 128;
#pragma unroll
          for (int kt = 0; kt < 4; kt++) {
            f16x8 a1 = *(const f16x8*)&h1r[(ro + kt * 32 + kg * 8) ^ sw];
            aR = MFMA16(a1, Wreg[0][kt], aR);
            aZ = MFMA16(a1, Wreg[1][kt], aZ);
            aH = MFMA16(a1, Wreg[2][kt], aH);
          }
          // x A-frag from LDS (f32 -> f16), swizzled chunk addressing
          const int xr = rt * 16 + lr;
          const float* xrow = &xbuf[cur][xr * 32];
          const int xs = xr & 7;
          float4 xa = *(const float4*)&xrow[((kg * 2    ) ^ xs) * 4];
          float4 xc = *(const float4*)&xrow[((kg * 2 + 1) ^ xs) * 4];
          f16x8 ax;
          ax[0] = (f16)xa.x; ax[1] = (f16)xa.y; ax[2] = (f16)xa.z; ax[3] = (f16)xa.w;
          ax[4] = (f16)xc.x; ax[5] = (f16)xc.y; ax[6] = (f16)xc.z; ax[7] = (f16)xc.w;
          f16x8 u0 = wlx[(wv     ) * 64 + lane];
          f16x8 u1 = wlx[(wv +  8) * 64 + lane];
          f16x8 u2 = wlx[(wv + 16) * 64 + lane];
          aR = MFMA16(ax, u0, aR);
          aZ = MFMA16(ax, u1, aZ);
          aI = MFMA16(ax, u2, aI);
#pragma unroll
          for (int i = 0; i < 4; i++) {
            float rg = fsig(aR[i]);
            float zg = fsig(aZ[i]);
            float nn = ftanh(fmaf(rg, aH[i], aI[i]));
            float hp = hs[rt][i];
            float hn = fmaxf(fmaf(zg, hp - nn, nn), 0.f);  // relu((1-z)n+zh)
            hs[rt][i] = hn;
            const int rr = rt * 16 + kg * 4 + i;
            h1w[(rr * 128 + d) ^ ((rr & 7) << 3)] = (f16)hn;
          }
        }
      }
    } else {
      if (p >= 1) {
#pragma unroll
        for (int rt = 0; rt < 2; rt++) {
          f32x4 aR = splat4(br_), aZ = splat4(bz_), aI = splat4(bin), aH = splat4(bhn);
          const int ro = (rt * 16 + lr) * 128;
#pragma unroll
          for (int kt = 0; kt < 4; kt++) {
            const int o = (ro + kt * 32 + kg * 8) ^ sw;
            f16x8 a1 = *(const f16x8*)&h1r[o];
            f16x8 a2 = *(const f16x8*)&h2r[o];
            f16x8 u0 = wl2[((wv     ) * 4 + kt) * 64 + lane];
            f16x8 u1 = wl2[((wv +  8) * 4 + kt) * 64 + lane];
            f16x8 u2 = wl2[((wv + 16) * 4 + kt) * 64 + lane];
            aR = MFMA16(a1, u0, aR);
            aZ = MFMA16(a1, u1, aZ);
            aI = MFMA16(a1, u2, aI);
            aR = MFMA16(a2, Wreg[0][kt], aR);
            aZ = MFMA16(a2, Wreg[1][kt], aZ);
            aH = MFMA16(a2, Wreg[2][kt], aH);
          }
#pragma unroll
          for (int i = 0; i < 4; i++) {
            float rg = fsig(aR[i]);
            float zg = fsig(aZ[i]);
            float nn = ftanh(fmaf(rg, aH[i], aI[i]));
            float hp = hs[rt][i];
            float hn = fmaxf(fmaf(zg, hp - nn, nn), 0.f);
            hs[rt][i] = hn;
            const int rr = rt * 16 + kg * 4 + i;
            h2w[(rr * 128 + d) ^ ((rr & 7) << 3)] = (f16)hn;
          }
        }
      }
    }
    __syncthreads();
  }

  // ---- epilogue: out[row,col] = h2 . wout[col,:] + bout[col]
  // phase TS=28 wrote h2[27] into h2b[(28&1)^1] = h2b[1]
  const int orow = tid >> 4;   // 0..63; valid rows < 32
  const int ocol = tid & 15;   // active < 10
  if (orow < BR && ocol < 10) {
    const f16* hb = h2b[1];
    float s = bout[ocol];
#pragma unroll 8
    for (int k = 0; k < 128; k++) {
      float hv = (float)hb[(orow * 128 + k) ^ ((orow & 7) << 3)];
      s = fmaf(hv, wout[ocol * 128 + k], s);
    }
    out[(size_t)(row0 + orow) * 10 + ocol] = s;
  }
}

extern "C" void kernel_launch(void* const* d_in, const int* in_sizes, int n_in,
                              void* d_out, int out_size, void* d_ws, size_t ws_size,
                              hipStream_t stream) {
  const float* x    = (const float*)d_in[0];
  const float* wih1 = (const float*)d_in[1];
  const float* whh1 = (const float*)d_in[2];
  const float* bih1 = (const float*)d_in[3];
  const float* bhh1 = (const float*)d_in[4];
  const float* wih2 = (const float*)d_in[5];
  const float* whh2 = (const float*)d_in[6];
  const float* bih2 = (const float*)d_in[7];
  const float* bhh2 = (const float*)d_in[8];
  const float* wout = (const float*)d_in[9];
  const float* bout = (const float*)d_in[10];
  f16* wsf   = (f16*)d_ws;
  float* out = (float*)d_out;

  prep_weights<<<312, 64, 0, stream>>>(wih1, whh1, wih2, whh2, wsf);
  gru_main<<<NROWS / BR, 1024, 0, stream>>>(x, bih1, bhh1, bih2, bhh2,
                                            wout, bout, wsf, out);
}